// Round 1
// baseline (362.350 us; speedup 1.0000x reference)
//
#include <hip/hip_runtime.h>
#include <math.h>

#define H 192
#define W 192
#define HW (H*W)          // 36864
#define CIN 32
#define COUT 32
#define NB 4
#define NPOS (NB*HW)      // 147456

// ---------------------------------------------------------------------------
// Kernel 1: fused 3x3 conv producing offset (18 ch) + modulator (9 ch, 2*sigmoid)
// One thread per (b,ho,wo). Weights staged in LDS, rows padded 27->28 so the
// per-tap weight read is 7x ds_read_b128 (uniform broadcast).
// ---------------------------------------------------------------------------
__global__ __launch_bounds__(256) void conv_offmod_kernel(
    const float* __restrict__ x,
    const float* __restrict__ w_off, const float* __restrict__ b_off,
    const float* __restrict__ w_mod, const float* __restrict__ b_mod,
    float* __restrict__ offs, float* __restrict__ modv)
{
    __shared__ float wl[288 * 28];   // [tap=ci*9+ky*3+kx][co], co 0..26 (27=pad)
    __shared__ float bl[27];
    const int tid = threadIdx.x;

    for (int i = tid; i < 288 * 27; i += 256) {
        int j  = i / 27;
        int co = i - j * 27;
        // w_off[co][ci][ky][kx] = w_off[co*288 + j]
        wl[j * 28 + co] = (co < 18) ? w_off[co * 288 + j] : w_mod[(co - 18) * 288 + j];
    }
    for (int i = tid; i < 288; i += 256) wl[i * 28 + 27] = 0.0f;
    if (tid < 27) bl[tid] = (tid < 18) ? b_off[tid] : b_mod[tid - 18];
    __syncthreads();

    const int pos = blockIdx.x * 256 + tid;
    const int b   = pos / HW;
    const int rem = pos - b * HW;
    const int ho  = rem / W;
    const int wo  = rem - ho * W;

    float acc[28];
    #pragma unroll
    for (int q = 0; q < 27; ++q) acc[q] = bl[q];
    acc[27] = 0.0f;

    const float* xb = x + (size_t)b * (CIN * HW);
    for (int ci = 0; ci < CIN; ++ci) {
        const float* xc = xb + ci * HW;
        #pragma unroll
        for (int ky = 0; ky < 3; ++ky) {
            const int iy = ho + ky - 1;
            const bool yok = ((unsigned)iy < (unsigned)H);
            #pragma unroll
            for (int kx = 0; kx < 3; ++kx) {
                const int ix = wo + kx - 1;
                const float xv = (yok && ((unsigned)ix < (unsigned)W)) ? xc[iy * W + ix] : 0.0f;
                const float4* wr =
                    reinterpret_cast<const float4*>(&wl[(ci * 9 + ky * 3 + kx) * 28]);
                #pragma unroll
                for (int q = 0; q < 7; ++q) {
                    float4 wv = wr[q];
                    acc[4*q+0] += xv * wv.x;
                    acc[4*q+1] += xv * wv.y;
                    acc[4*q+2] += xv * wv.z;
                    acc[4*q+3] += xv * wv.w;
                }
            }
        }
    }

    float* ob = offs + (size_t)b * (18 * HW) + rem;
    #pragma unroll
    for (int co = 0; co < 18; ++co) ob[co * HW] = acc[co];
    float* mb = modv + (size_t)b * (9 * HW) + rem;
    #pragma unroll
    for (int j = 0; j < 9; ++j) mb[j * HW] = 2.0f / (1.0f + expf(-acc[18 + j]));
}

// ---------------------------------------------------------------------------
// Kernel 2: deformable sampling + 288->32 contraction.
// One thread per (b,ho,wo). w_reg staged in LDS as [(c*9+k)*32 + o] so the
// inner o-loop is 8x ds_read_b128 (uniform broadcast) + 32 FMA.
// Corner validity & mask folded into the 4 bilinear weights (== ref g*valid).
// ---------------------------------------------------------------------------
__global__ __launch_bounds__(256) void deform_kernel(
    const float* __restrict__ x,
    const float* __restrict__ offs, const float* __restrict__ modv,
    const float* __restrict__ w_reg, float* __restrict__ out)
{
    __shared__ float wl[288 * 32];   // [(c*9+k)][o]
    const int tid = threadIdx.x;
    for (int i = tid; i < 288 * 32; i += 256) {
        int o  = i & 31;
        int ck = i >> 5;
        wl[i] = w_reg[o * 288 + ck];   // w_reg[o][c][k] = o*288 + ck
    }
    __syncthreads();

    const int pos = blockIdx.x * 256 + tid;
    const int b   = pos / HW;
    const int rem = pos - b * HW;
    const int ho  = rem / W;
    const int wo  = rem - ho * W;

    const float* xb = x    + (size_t)b * (CIN * HW);
    const float* ob = offs + (size_t)b * (18 * HW) + rem;
    const float* mb = modv + (size_t)b * (9 * HW) + rem;

    float acc[32];
    #pragma unroll
    for (int o = 0; o < 32; ++o) acc[o] = 0.0f;

    for (int k = 0; k < 9; ++k) {
        const int ky = k / 3;
        const int kx = k - ky * 3;
        const float oy = ob[(2 * k) * HW];
        const float ox = ob[(2 * k + 1) * HW];
        const float m  = mb[k * HW];

        const float py  = oy + (float)(ho - 1 + ky);
        const float px  = ox + (float)(wo - 1 + kx);
        const float y0f = floorf(py);
        const float x0f = floorf(px);
        const float wy  = py - y0f;
        const float wx  = px - x0f;
        const int y0 = (int)y0f, x0 = (int)x0f;
        const int y1 = y0 + 1,  x1 = x0 + 1;

        const float vy0 = ((unsigned)y0 < (unsigned)H) ? 1.0f : 0.0f;
        const float vy1 = ((unsigned)y1 < (unsigned)H) ? 1.0f : 0.0f;
        const float vx0 = ((unsigned)x0 < (unsigned)W) ? 1.0f : 0.0f;
        const float vx1 = ((unsigned)x1 < (unsigned)W) ? 1.0f : 0.0f;

        const float w00 = (1.0f - wy) * (1.0f - wx) * vy0 * vx0 * m;
        const float w01 = (1.0f - wy) * wx          * vy0 * vx1 * m;
        const float w10 = wy * (1.0f - wx)          * vy1 * vx0 * m;
        const float w11 = wy * wx                   * vy1 * vx1 * m;

        const int cy0 = min(max(y0, 0), H - 1), cy1 = min(max(y1, 0), H - 1);
        const int cx0 = min(max(x0, 0), W - 1), cx1 = min(max(x1, 0), W - 1);
        const int l00 = cy0 * W + cx0, l01 = cy0 * W + cx1;
        const int l10 = cy1 * W + cx0, l11 = cy1 * W + cx1;

        for (int c = 0; c < CIN; ++c) {
            const float* xc = xb + c * HW;
            const float v = w00 * xc[l00] + w01 * xc[l01]
                          + w10 * xc[l10] + w11 * xc[l11];
            const float4* wr = reinterpret_cast<const float4*>(&wl[(c * 9 + k) * 32]);
            #pragma unroll
            for (int q = 0; q < 8; ++q) {
                float4 wv = wr[q];
                acc[4*q+0] += v * wv.x;
                acc[4*q+1] += v * wv.y;
                acc[4*q+2] += v * wv.z;
                acc[4*q+3] += v * wv.w;
            }
        }
    }

    float* yb = out + (size_t)b * (COUT * HW) + rem;
    #pragma unroll
    for (int o = 0; o < COUT; ++o) yb[o * HW] = acc[o];
}

// ---------------------------------------------------------------------------
extern "C" void kernel_launch(void* const* d_in, const int* in_sizes, int n_in,
                              void* d_out, int out_size, void* d_ws, size_t ws_size,
                              hipStream_t stream) {
    const float* x     = (const float*)d_in[0];
    const float* w_off = (const float*)d_in[1];
    const float* b_off = (const float*)d_in[2];
    const float* w_mod = (const float*)d_in[3];
    const float* b_mod = (const float*)d_in[4];
    const float* w_reg = (const float*)d_in[5];
    float* out = (float*)d_out;

    // workspace: offset (4*18*HW floats) then modulator (4*9*HW floats) = 15.2 MiB
    float* offs = (float*)d_ws;
    float* modv = offs + (size_t)NB * 18 * HW;

    dim3 grid(NPOS / 256), blk(256);
    conv_offmod_kernel<<<grid, blk, 0, stream>>>(x, w_off, b_off, w_mod, b_mod, offs, modv);
    deform_kernel<<<grid, blk, 0, stream>>>(x, offs, modv, w_reg, out);
}

// Round 2
// 206.121 us; speedup vs baseline: 1.7579x; 1.7579x over previous
//
#include <hip/hip_runtime.h>
#include <math.h>

#define H 192
#define W 192
#define HW (H*W)          // 36864
#define CIN 32
#define COUT 32
#define NB 4
#define NPOS (NB*HW)      // 147456
#define NBLK (NPOS/256)   // 576

// bijective XCD-chunked swizzle (NBLK % 8 == 0): XCD x gets a contiguous
// pos-chunk -> per-XCD L2 working set ~2.4 MB (fits 4 MB).
__device__ __forceinline__ int swz_block(int bid) {
    return (bid & 7) * (NBLK / 8) + (bid >> 3);
}

// ---------------------------------------------------------------------------
// Kernel A: NCHW -> NHWC transpose of x. block = 32c x 64hw tile.
// ---------------------------------------------------------------------------
__global__ __launch_bounds__(256) void transpose_kernel(
    const float* __restrict__ x, float* __restrict__ xt)
{
    __shared__ float lds[32][65];
    const int tid = threadIdx.x;
    const int b   = blockIdx.x / (HW / 64);
    const int hw0 = (blockIdx.x % (HW / 64)) * 64;
    const float* xb = x + (size_t)b * CIN * HW;

    #pragma unroll
    for (int r = 0; r < 8; ++r) {
        const int c  = (tid >> 6) + 4 * r;
        const int hw = tid & 63;
        lds[c][hw] = xb[(size_t)c * HW + hw0 + hw];
    }
    __syncthreads();

    const int hw = tid >> 2;
    const int cg = (tid & 3) * 8;
    float* dst = xt + ((size_t)b * HW + hw0 + hw) * 32 + cg;
    float4 v0, v1;
    v0.x = lds[cg + 0][hw]; v0.y = lds[cg + 1][hw];
    v0.z = lds[cg + 2][hw]; v0.w = lds[cg + 3][hw];
    v1.x = lds[cg + 4][hw]; v1.y = lds[cg + 5][hw];
    v1.z = lds[cg + 6][hw]; v1.w = lds[cg + 7][hw];
    *reinterpret_cast<float4*>(dst)     = v0;
    *reinterpret_cast<float4*>(dst + 4) = v1;
}

// ---------------------------------------------------------------------------
// Kernel B (fast path): fused offset/modulator conv + deformable conv.
// One thread per (b,ho,wo); x consumed in NHWC. LDS weight buffer is staged
// twice (conv weights, then deform weights) with a barrier between phases.
// ---------------------------------------------------------------------------
__global__ __launch_bounds__(256) void fused_deform_kernel(
    const float* __restrict__ xt,
    const float* __restrict__ w_off, const float* __restrict__ b_off,
    const float* __restrict__ w_mod, const float* __restrict__ b_mod,
    const float* __restrict__ w_reg, float* __restrict__ out)
{
    __shared__ float wl[288 * 32];   // phase1: [(ci*9+t)*28+co]; phase2: [(c*9+k)*32+o]
    __shared__ float bl[28];
    const int tid = threadIdx.x;

    // ---- stage conv weights: [(ci*9+t)][co], rows padded 27->28 ----
    for (int i = tid; i < 288 * 27; i += 256) {
        const int j  = i / 27;
        const int co = i - j * 27;
        wl[j * 28 + co] = (co < 18) ? w_off[co * 288 + j] : w_mod[(co - 18) * 288 + j];
    }
    for (int i = tid; i < 288; i += 256) wl[i * 28 + 27] = 0.0f;
    if (tid < 28) bl[tid] = (tid < 18) ? b_off[tid] : (tid < 27 ? b_mod[tid - 18] : 0.0f);
    __syncthreads();

    const int pos = swz_block(blockIdx.x) * 256 + tid;
    const int b   = pos / HW;
    const int rem = pos - b * HW;
    const int ho  = rem / W;
    const int wo  = rem - ho * W;

    const float* xb = xt + (size_t)b * HW * 32;

    // ---- phase 1: 3x3 conv -> acc[0..17]=offset, acc[18..26]=pre-sigmoid ----
    float acc[28];
    #pragma unroll
    for (int q = 0; q < 27; ++q) acc[q] = bl[q];
    acc[27] = 0.0f;

    for (int t = 0; t < 9; ++t) {                 // runtime tap loop
        const int ky = t / 3, kx = t - (t / 3) * 3;
        const int iy = ho + ky - 1, ix = wo + kx - 1;
        const bool ok = ((unsigned)iy < (unsigned)H) && ((unsigned)ix < (unsigned)W);
        const float msk = ok ? 1.0f : 0.0f;
        const int cy = min(max(iy, 0), H - 1), cx = min(max(ix, 0), W - 1);
        const float4* src = reinterpret_cast<const float4*>(xb + ((size_t)(cy * W + cx)) * 32);
        const int wbase_t = t * 28;
        #pragma unroll
        for (int g = 0; g < 8; ++g) {             // 8 independent 16B loads -> MLP
            float4 v = src[g];
            v.x *= msk; v.y *= msk; v.z *= msk; v.w *= msk;
            #pragma unroll
            for (int j = 0; j < 4; ++j) {
                const float xv = (j == 0) ? v.x : (j == 1) ? v.y : (j == 2) ? v.z : v.w;
                const float* wr = &wl[(4 * g + j) * 252 + wbase_t];
                #pragma unroll
                for (int q = 0; q < 7; ++q) {
                    const float4 wv = *reinterpret_cast<const float4*>(&wr[q * 4]);
                    acc[4 * q + 0] += xv * wv.x;
                    acc[4 * q + 1] += xv * wv.y;
                    acc[4 * q + 2] += xv * wv.z;
                    acc[4 * q + 3] += xv * wv.w;
                }
            }
        }
    }

    // modulator = 2*sigmoid
    #pragma unroll
    for (int j = 18; j < 27; ++j) acc[j] = 2.0f / (1.0f + __expf(-acc[j]));

    // ---- restage LDS with deform weights: [(c*9+k)*32 + o] ----
    __syncthreads();
    for (int i = tid; i < 288 * 32; i += 256) {
        const int o  = i & 31;
        const int ck = i >> 5;
        wl[i] = w_reg[o * 288 + ck];
    }
    __syncthreads();

    // ---- phase 2: deformable sampling + 288->32 contraction ----
    float acc2[32];
    #pragma unroll
    for (int o = 0; o < 32; ++o) acc2[o] = 0.0f;

    #pragma unroll
    for (int k = 0; k < 9; ++k) {                 // unrolled: static acc[] indexing
        const int ky = k / 3, kx = k - (k / 3) * 3;
        const float oy = acc[2 * k];
        const float ox = acc[2 * k + 1];
        const float m  = acc[18 + k];

        const float py  = oy + (float)(ho - 1 + ky);
        const float px  = ox + (float)(wo - 1 + kx);
        const float y0f = floorf(py);
        const float x0f = floorf(px);
        const float wy  = py - y0f;
        const float wx  = px - x0f;
        const int y0 = (int)y0f, x0 = (int)x0f;
        const int y1 = y0 + 1,  x1 = x0 + 1;

        const float vy0 = ((unsigned)y0 < (unsigned)H) ? 1.0f : 0.0f;
        const float vy1 = ((unsigned)y1 < (unsigned)H) ? 1.0f : 0.0f;
        const float vx0 = ((unsigned)x0 < (unsigned)W) ? 1.0f : 0.0f;
        const float vx1 = ((unsigned)x1 < (unsigned)W) ? 1.0f : 0.0f;

        const float w00 = (1.0f - wy) * (1.0f - wx) * vy0 * vx0 * m;
        const float w01 = (1.0f - wy) * wx          * vy0 * vx1 * m;
        const float w10 = wy * (1.0f - wx)          * vy1 * vx0 * m;
        const float w11 = wy * wx                   * vy1 * vx1 * m;

        const int cy0 = min(max(y0, 0), H - 1), cy1 = min(max(y1, 0), H - 1);
        const int cx0 = min(max(x0, 0), W - 1), cx1 = min(max(x1, 0), W - 1);
        const float4* p00 = reinterpret_cast<const float4*>(xb + ((size_t)(cy0 * W + cx0)) * 32);
        const float4* p01 = reinterpret_cast<const float4*>(xb + ((size_t)(cy0 * W + cx1)) * 32);
        const float4* p10 = reinterpret_cast<const float4*>(xb + ((size_t)(cy1 * W + cx0)) * 32);
        const float4* p11 = reinterpret_cast<const float4*>(xb + ((size_t)(cy1 * W + cx1)) * 32);

        for (int g = 0; g < 8; ++g) {             // runtime channel-group loop
            const float4 A = p00[g], Bv = p01[g], Cv = p10[g], Dv = p11[g];
            float4 v;
            v.x = w00 * A.x + w01 * Bv.x + w10 * Cv.x + w11 * Dv.x;
            v.y = w00 * A.y + w01 * Bv.y + w10 * Cv.y + w11 * Dv.y;
            v.z = w00 * A.z + w01 * Bv.z + w10 * Cv.z + w11 * Dv.z;
            v.w = w00 * A.w + w01 * Bv.w + w10 * Cv.w + w11 * Dv.w;
            #pragma unroll
            for (int j = 0; j < 4; ++j) {
                const float vj = (j == 0) ? v.x : (j == 1) ? v.y : (j == 2) ? v.z : v.w;
                const float* wr = &wl[(4 * g + j) * 288 + k * 32];
                #pragma unroll
                for (int q = 0; q < 8; ++q) {
                    const float4 wv = *reinterpret_cast<const float4*>(&wr[q * 4]);
                    acc2[4 * q + 0] += vj * wv.x;
                    acc2[4 * q + 1] += vj * wv.y;
                    acc2[4 * q + 2] += vj * wv.z;
                    acc2[4 * q + 3] += vj * wv.w;
                }
            }
        }
    }

    float* yb = out + (size_t)b * COUT * HW + rem;
    #pragma unroll
    for (int o = 0; o < COUT; ++o) yb[o * HW] = acc2[o];
}

// ---------------------------------------------------------------------------
// Fallback path (round-0 kernels, proven; used only if ws too small)
// ---------------------------------------------------------------------------
__global__ __launch_bounds__(256) void conv_offmod_kernel(
    const float* __restrict__ x,
    const float* __restrict__ w_off, const float* __restrict__ b_off,
    const float* __restrict__ w_mod, const float* __restrict__ b_mod,
    float* __restrict__ offs, float* __restrict__ modv)
{
    __shared__ float wl[288 * 28];
    __shared__ float bl[27];
    const int tid = threadIdx.x;

    for (int i = tid; i < 288 * 27; i += 256) {
        int j  = i / 27;
        int co = i - j * 27;
        wl[j * 28 + co] = (co < 18) ? w_off[co * 288 + j] : w_mod[(co - 18) * 288 + j];
    }
    for (int i = tid; i < 288; i += 256) wl[i * 28 + 27] = 0.0f;
    if (tid < 27) bl[tid] = (tid < 18) ? b_off[tid] : b_mod[tid - 18];
    __syncthreads();

    const int pos = blockIdx.x * 256 + tid;
    const int b   = pos / HW;
    const int rem = pos - b * HW;
    const int ho  = rem / W;
    const int wo  = rem - ho * W;

    float acc[28];
    #pragma unroll
    for (int q = 0; q < 27; ++q) acc[q] = bl[q];
    acc[27] = 0.0f;

    const float* xb = x + (size_t)b * (CIN * HW);
    for (int ci = 0; ci < CIN; ++ci) {
        const float* xc = xb + ci * HW;
        #pragma unroll
        for (int ky = 0; ky < 3; ++ky) {
            const int iy = ho + ky - 1;
            const bool yok = ((unsigned)iy < (unsigned)H);
            #pragma unroll
            for (int kx = 0; kx < 3; ++kx) {
                const int ix = wo + kx - 1;
                const float xv = (yok && ((unsigned)ix < (unsigned)W)) ? xc[iy * W + ix] : 0.0f;
                const float4* wr =
                    reinterpret_cast<const float4*>(&wl[(ci * 9 + ky * 3 + kx) * 28]);
                #pragma unroll
                for (int q = 0; q < 7; ++q) {
                    float4 wv = wr[q];
                    acc[4*q+0] += xv * wv.x;
                    acc[4*q+1] += xv * wv.y;
                    acc[4*q+2] += xv * wv.z;
                    acc[4*q+3] += xv * wv.w;
                }
            }
        }
    }

    float* ob = offs + (size_t)b * (18 * HW) + rem;
    #pragma unroll
    for (int co = 0; co < 18; ++co) ob[co * HW] = acc[co];
    float* mb = modv + (size_t)b * (9 * HW) + rem;
    #pragma unroll
    for (int j = 0; j < 9; ++j) mb[j * HW] = 2.0f / (1.0f + expf(-acc[18 + j]));
}

__global__ __launch_bounds__(256) void deform_kernel(
    const float* __restrict__ x,
    const float* __restrict__ offs, const float* __restrict__ modv,
    const float* __restrict__ w_reg, float* __restrict__ out)
{
    __shared__ float wl[288 * 32];
    const int tid = threadIdx.x;
    for (int i = tid; i < 288 * 32; i += 256) {
        int o  = i & 31;
        int ck = i >> 5;
        wl[i] = w_reg[o * 288 + ck];
    }
    __syncthreads();

    const int pos = blockIdx.x * 256 + tid;
    const int b   = pos / HW;
    const int rem = pos - b * HW;
    const int ho  = rem / W;
    const int wo  = rem - ho * W;

    const float* xb = x    + (size_t)b * (CIN * HW);
    const float* ob = offs + (size_t)b * (18 * HW) + rem;
    const float* mb = modv + (size_t)b * (9 * HW) + rem;

    float acc[32];
    #pragma unroll
    for (int o = 0; o < 32; ++o) acc[o] = 0.0f;

    for (int k = 0; k < 9; ++k) {
        const int ky = k / 3;
        const int kx = k - ky * 3;
        const float oy = ob[(2 * k) * HW];
        const float ox = ob[(2 * k + 1) * HW];
        const float m  = mb[k * HW];

        const float py  = oy + (float)(ho - 1 + ky);
        const float px  = ox + (float)(wo - 1 + kx);
        const float y0f = floorf(py);
        const float x0f = floorf(px);
        const float wy  = py - y0f;
        const float wx  = px - x0f;
        const int y0 = (int)y0f, x0 = (int)x0f;
        const int y1 = y0 + 1,  x1 = x0 + 1;

        const float vy0 = ((unsigned)y0 < (unsigned)H) ? 1.0f : 0.0f;
        const float vy1 = ((unsigned)y1 < (unsigned)H) ? 1.0f : 0.0f;
        const float vx0 = ((unsigned)x0 < (unsigned)W) ? 1.0f : 0.0f;
        const float vx1 = ((unsigned)x1 < (unsigned)W) ? 1.0f : 0.0f;

        const float w00 = (1.0f - wy) * (1.0f - wx) * vy0 * vx0 * m;
        const float w01 = (1.0f - wy) * wx          * vy0 * vx1 * m;
        const float w10 = wy * (1.0f - wx)          * vy1 * vx0 * m;
        const float w11 = wy * wx                   * vy1 * vx1 * m;

        const int cy0 = min(max(y0, 0), H - 1), cy1 = min(max(y1, 0), H - 1);
        const int cx0 = min(max(x0, 0), W - 1), cx1 = min(max(x1, 0), W - 1);
        const int l00 = cy0 * W + cx0, l01 = cy0 * W + cx1;
        const int l10 = cy1 * W + cx0, l11 = cy1 * W + cx1;

        for (int c = 0; c < CIN; ++c) {
            const float* xc = xb + c * HW;
            const float v = w00 * xc[l00] + w01 * xc[l01]
                          + w10 * xc[l10] + w11 * xc[l11];
            const float4* wr = reinterpret_cast<const float4*>(&wl[(c * 9 + k) * 32]);
            #pragma unroll
            for (int q = 0; q < 8; ++q) {
                float4 wv = wr[q];
                acc[4*q+0] += v * wv.x;
                acc[4*q+1] += v * wv.y;
                acc[4*q+2] += v * wv.z;
                acc[4*q+3] += v * wv.w;
            }
        }
    }

    float* yb = out + (size_t)b * (COUT * HW) + rem;
    #pragma unroll
    for (int o = 0; o < COUT; ++o) yb[o * HW] = acc[o];
}

// ---------------------------------------------------------------------------
extern "C" void kernel_launch(void* const* d_in, const int* in_sizes, int n_in,
                              void* d_out, int out_size, void* d_ws, size_t ws_size,
                              hipStream_t stream) {
    const float* x     = (const float*)d_in[0];
    const float* w_off = (const float*)d_in[1];
    const float* b_off = (const float*)d_in[2];
    const float* w_mod = (const float*)d_in[3];
    const float* b_mod = (const float*)d_in[4];
    const float* w_reg = (const float*)d_in[5];
    float* out = (float*)d_out;

    const size_t need_fast = (size_t)NPOS * 32 * sizeof(float);   // 18.9 MB NHWC copy
    if (ws_size >= need_fast) {
        float* xt = (float*)d_ws;
        transpose_kernel<<<dim3(NB * (HW / 64)), dim3(256), 0, stream>>>(x, xt);
        fused_deform_kernel<<<dim3(NBLK), dim3(256), 0, stream>>>(
            xt, w_off, b_off, w_mod, b_mod, w_reg, out);
    } else {
        float* offs = (float*)d_ws;
        float* modv = offs + (size_t)NB * 18 * HW;
        dim3 grid(NBLK), blk(256);
        conv_offmod_kernel<<<grid, blk, 0, stream>>>(x, w_off, b_off, w_mod, b_mod, offs, modv);
        deform_kernel<<<grid, blk, 0, stream>>>(x, offs, modv, w_reg, out);
    }
}

// Round 3
// 128.464 us; speedup vs baseline: 2.8206x; 1.6045x over previous
//
#include <hip/hip_runtime.h>
#include <hip/hip_bf16.h>
#include <math.h>

#define H 192
#define W 192
#define HW (H*W)          // 36864
#define CIN 32
#define COUT 32
#define NB 4
#define NPOS (NB*HW)      // 147456
#define NBLK_F (NPOS/128) // 1152 blocks of 512 threads (8 waves x 16 pos)
#define NBLK0 (NPOS/256)  // 576 fallback blocks

typedef __attribute__((ext_vector_type(8))) short bf16x8;
typedef __attribute__((ext_vector_type(4))) float f32x4;

__device__ __forceinline__ short f2bf(float f) {
    __hip_bfloat16 h = __float2bfloat16(f);   // RNE; compiler emits v_cvt_pk_bf16_f32
    short s; __builtin_memcpy(&s, &h, sizeof(s));
    return s;
}

// bijective XCD-chunked swizzle (nblk % 8 == 0)
__device__ __forceinline__ int swz8(int bid, int nblk) {
    return (bid & 7) * (nblk >> 3) + (bid >> 3);
}

// ---------------------------------------------------------------------------
// Kernel A: NCHW -> NHWC transpose of x (proven in round 1).
// ---------------------------------------------------------------------------
__global__ __launch_bounds__(256) void transpose_kernel(
    const float* __restrict__ x, float* __restrict__ xt)
{
    __shared__ float lds[32][65];
    const int tid = threadIdx.x;
    const int b   = blockIdx.x / (HW / 64);
    const int hw0 = (blockIdx.x % (HW / 64)) * 64;
    const float* xb = x + (size_t)b * CIN * HW;

    #pragma unroll
    for (int r = 0; r < 8; ++r) {
        const int c  = (tid >> 6) + 4 * r;
        const int hw = tid & 63;
        lds[c][hw] = xb[(size_t)c * HW + hw0 + hw];
    }
    __syncthreads();

    const int hw = tid >> 2;
    const int cg = (tid & 3) * 8;
    float* dst = xt + ((size_t)b * HW + hw0 + hw) * 32 + cg;
    float4 v0, v1;
    v0.x = lds[cg + 0][hw]; v0.y = lds[cg + 1][hw];
    v0.z = lds[cg + 2][hw]; v0.w = lds[cg + 3][hw];
    v1.x = lds[cg + 4][hw]; v1.y = lds[cg + 5][hw];
    v1.z = lds[cg + 6][hw]; v1.w = lds[cg + 7][hw];
    *reinterpret_cast<float4*>(dst)     = v0;
    *reinterpret_cast<float4*>(dst + 4) = v1;
}

// ---------------------------------------------------------------------------
// Kernel B: fully fused MFMA deformable conv.
// Wave = 16 positions (fragment M) x 4 channel-groups (fragment K-split).
// Phase 1: 3x3 conv -> 27ch via 18 MFMA; bias+sigmoid; stash in per-wave LDS.
// Phase 2: per tap, fp32 bilinear gather/interp of 8 channels/lane -> bf16
//          A-fragment; 2 MFMA per tap (out cols 0-15, 16-31).
// B-fragments pre-staged in LDS in exact lane layout: B[k=c][col=o].
// ---------------------------------------------------------------------------
__global__ __launch_bounds__(512, 4) void deform_mfma_kernel(
    const float* __restrict__ xt,
    const float* __restrict__ w_off, const float* __restrict__ b_off,
    const float* __restrict__ w_mod, const float* __restrict__ b_mod,
    const float* __restrict__ w_reg, float* __restrict__ out)
{
    __shared__ short b1s[9][2][64][8];   // phase1 weights (w_off||w_mod), 18 KB
    __shared__ short b2s[9][2][64][8];   // phase2 weights (w_reg),        18 KB
    __shared__ float om[8][16][28];      // per-wave offset/mod exchange,  14 KB
    __shared__ float bl[32];

    const int tid = threadIdx.x;

    // ---- stage B-fragments: elem e of lane l = B[k = 8*(l>>4)+e][col = 16n+(l&15)]
    for (int i = tid; i < 9 * 2 * 64 * 8; i += 512) {
        const int e = i & 7, l = (i >> 3) & 63, n = (i >> 9) & 1, t = i >> 10;
        const int o = 16 * n + (l & 15);
        const int c = 8 * (l >> 4) + e;
        const int idx = c * 9 + t;                    // [ci][ky][kx] flat
        const float v1 = (o < 18) ? w_off[o * 288 + idx]
                        : (o < 27 ? w_mod[(o - 18) * 288 + idx] : 0.0f);
        b1s[t][n][l][e] = f2bf(v1);
        b2s[t][n][l][e] = f2bf(w_reg[o * 288 + idx]);
    }
    if (tid < 32) bl[tid] = (tid < 18) ? b_off[tid] : (tid < 27 ? b_mod[tid - 18] : 0.0f);
    __syncthreads();

    const int lane = tid & 63;
    const int wv   = tid >> 6;
    const int prow = lane & 15;   // position within wave tile (A-row role)
    const int kgrp = lane >> 4;   // channel group (A k-split role)
    const int col  = prow;        // C/D column role (out channel)

    const int pos_wave = swz8(blockIdx.x, NBLK_F) * 128 + wv * 16;
    const int b    = pos_wave / HW;
    const int rem0 = pos_wave - b * HW;      // wave never crosses a row (W%16==0)
    const int ho   = rem0 / W;
    const int wo0  = rem0 - ho * W;
    const int wo   = wo0 + prow;

    const float* xb = xt + (size_t)b * HW * 32;

    // ---- phase 1: offset/modulator conv via MFMA ----
    f32x4 c10 = {0.f, 0.f, 0.f, 0.f}, c11 = {0.f, 0.f, 0.f, 0.f};
    #pragma unroll
    for (int t = 0; t < 9; ++t) {
        const int ty = t / 3, tx = t - (t / 3) * 3;
        const int iy = ho + ty - 1, ix = wo + tx - 1;
        const bool ok = ((unsigned)iy < (unsigned)H) && ((unsigned)ix < (unsigned)W);
        const int cy = min(max(iy, 0), H - 1), cx = min(max(ix, 0), W - 1);
        const float* s = xb + (size_t)(cy * W + cx) * 32 + 8 * kgrp;
        const f32x4 u0 = *reinterpret_cast<const f32x4*>(s);
        const f32x4 u1 = *reinterpret_cast<const f32x4*>(s + 4);
        bf16x8 a;
        #pragma unroll
        for (int j = 0; j < 4; ++j) {
            a[j]     = f2bf(ok ? u0[j] : 0.0f);
            a[j + 4] = f2bf(ok ? u1[j] : 0.0f);
        }
        const bf16x8 wb0 = *reinterpret_cast<const bf16x8*>(&b1s[t][0][lane][0]);
        const bf16x8 wb1 = *reinterpret_cast<const bf16x8*>(&b1s[t][1][lane][0]);
        c10 = __builtin_amdgcn_mfma_f32_16x16x32_bf16(a, wb0, c10, 0, 0, 0);
        c11 = __builtin_amdgcn_mfma_f32_16x16x32_bf16(a, wb1, c11, 0, 0, 0);
    }

    // ---- bias + sigmoid, stash to per-wave LDS (C/D: row=(lane>>4)*4+r, col) ----
    {
        const float bias0 = bl[col], bias1 = bl[16 + col];
        #pragma unroll
        for (int r = 0; r < 4; ++r) {
            const int prc = kgrp * 4 + r;
            om[wv][prc][col] = c10[r] + bias0;
            if (col < 11) {                         // channels 16..26 live in tile1
                float v = c11[r] + bias1;
                if (col >= 2) v = 2.0f / (1.0f + __expf(-v));   // ch 18..26: 2*sigmoid
                om[wv][prc][16 + col] = v;
            }
        }
    }
    // same-wave LDS write->read: compiler inserts lgkmcnt (conservative aliasing)

    f32x4 omr[7];
    #pragma unroll
    for (int q = 0; q < 7; ++q)
        omr[q] = *reinterpret_cast<const f32x4*>(&om[wv][prow][q * 4]);

    // ---- phase 2: deformable sampling + MFMA contraction ----
    f32x4 c20 = {0.f, 0.f, 0.f, 0.f}, c21 = {0.f, 0.f, 0.f, 0.f};
    #pragma unroll
    for (int k = 0; k < 9; ++k) {
        const int ky = k / 3, kx = k - (k / 3) * 3;
        const float oy = omr[(2 * k) >> 2][(2 * k) & 3];
        const float ox = omr[(2 * k + 1) >> 2][(2 * k + 1) & 3];
        const float m  = omr[(18 + k) >> 2][(18 + k) & 3];

        const float py  = oy + (float)(ho - 1 + ky);
        const float px  = ox + (float)(wo - 1 + kx);
        const float y0f = floorf(py);
        const float x0f = floorf(px);
        const float wy  = py - y0f;
        const float wx  = px - x0f;
        const int y0 = (int)y0f, x0 = (int)x0f;
        const int y1 = y0 + 1,  x1 = x0 + 1;

        const float vy0 = ((unsigned)y0 < (unsigned)H) ? 1.0f : 0.0f;
        const float vy1 = ((unsigned)y1 < (unsigned)H) ? 1.0f : 0.0f;
        const float vx0 = ((unsigned)x0 < (unsigned)W) ? 1.0f : 0.0f;
        const float vx1 = ((unsigned)x1 < (unsigned)W) ? 1.0f : 0.0f;

        const float w00 = (1.0f - wy) * (1.0f - wx) * vy0 * vx0 * m;
        const float w01 = (1.0f - wy) * wx          * vy0 * vx1 * m;
        const float w10 = wy * (1.0f - wx)          * vy1 * vx0 * m;
        const float w11 = wy * wx                   * vy1 * vx1 * m;

        const int cy0 = min(max(y0, 0), H - 1), cy1 = min(max(y1, 0), H - 1);
        const int cx0 = min(max(x0, 0), W - 1), cx1 = min(max(x1, 0), W - 1);
        const float* q00 = xb + (size_t)(cy0 * W + cx0) * 32 + 8 * kgrp;
        const float* q01 = xb + (size_t)(cy0 * W + cx1) * 32 + 8 * kgrp;
        const float* q10 = xb + (size_t)(cy1 * W + cx0) * 32 + 8 * kgrp;
        const float* q11 = xb + (size_t)(cy1 * W + cx1) * 32 + 8 * kgrp;

        const f32x4 A0 = *reinterpret_cast<const f32x4*>(q00);
        const f32x4 A1 = *reinterpret_cast<const f32x4*>(q00 + 4);
        const f32x4 B0 = *reinterpret_cast<const f32x4*>(q01);
        const f32x4 B1 = *reinterpret_cast<const f32x4*>(q01 + 4);
        const f32x4 C0 = *reinterpret_cast<const f32x4*>(q10);
        const f32x4 C1 = *reinterpret_cast<const f32x4*>(q10 + 4);
        const f32x4 D0 = *reinterpret_cast<const f32x4*>(q11);
        const f32x4 D1 = *reinterpret_cast<const f32x4*>(q11 + 4);

        bf16x8 a;
        #pragma unroll
        for (int j = 0; j < 4; ++j) {
            a[j]     = f2bf(w00 * A0[j] + w01 * B0[j] + w10 * C0[j] + w11 * D0[j]);
            a[j + 4] = f2bf(w00 * A1[j] + w01 * B1[j] + w10 * C1[j] + w11 * D1[j]);
        }
        const bf16x8 wb0 = *reinterpret_cast<const bf16x8*>(&b2s[k][0][lane][0]);
        const bf16x8 wb1 = *reinterpret_cast<const bf16x8*>(&b2s[k][1][lane][0]);
        c20 = __builtin_amdgcn_mfma_f32_16x16x32_bf16(a, wb0, c20, 0, 0, 0);
        c21 = __builtin_amdgcn_mfma_f32_16x16x32_bf16(a, wb1, c21, 0, 0, 0);
    }

    // ---- epilogue: C/D row = kgrp*4+r (position), col / col+16 (channel) ----
    float* yb = out + (size_t)b * COUT * HW;
    const int hwb = rem0 + kgrp * 4;
    #pragma unroll
    for (int r = 0; r < 4; ++r) {
        yb[(size_t)col * HW + hwb + r]        = c20[r];
        yb[(size_t)(col + 16) * HW + hwb + r] = c21[r];
    }
}

// ---------------------------------------------------------------------------
// Fallback path (round-0 kernels, proven; used only if ws too small)
// ---------------------------------------------------------------------------
__global__ __launch_bounds__(256) void conv_offmod_kernel(
    const float* __restrict__ x,
    const float* __restrict__ w_off, const float* __restrict__ b_off,
    const float* __restrict__ w_mod, const float* __restrict__ b_mod,
    float* __restrict__ offs, float* __restrict__ modv)
{
    __shared__ float wl[288 * 28];
    __shared__ float bl[27];
    const int tid = threadIdx.x;

    for (int i = tid; i < 288 * 27; i += 256) {
        int j  = i / 27;
        int co = i - j * 27;
        wl[j * 28 + co] = (co < 18) ? w_off[co * 288 + j] : w_mod[(co - 18) * 288 + j];
    }
    for (int i = tid; i < 288; i += 256) wl[i * 28 + 27] = 0.0f;
    if (tid < 27) bl[tid] = (tid < 18) ? b_off[tid] : b_mod[tid - 18];
    __syncthreads();

    const int pos = blockIdx.x * 256 + tid;
    const int b   = pos / HW;
    const int rem = pos - b * HW;
    const int ho  = rem / W;
    const int wo  = rem - ho * W;

    float acc[28];
    #pragma unroll
    for (int q = 0; q < 27; ++q) acc[q] = bl[q];
    acc[27] = 0.0f;

    const float* xb = x + (size_t)b * (CIN * HW);
    for (int ci = 0; ci < CIN; ++ci) {
        const float* xc = xb + ci * HW;
        #pragma unroll
        for (int ky = 0; ky < 3; ++ky) {
            const int iy = ho + ky - 1;
            const bool yok = ((unsigned)iy < (unsigned)H);
            #pragma unroll
            for (int kx = 0; kx < 3; ++kx) {
                const int ix = wo + kx - 1;
                const float xv = (yok && ((unsigned)ix < (unsigned)W)) ? xc[iy * W + ix] : 0.0f;
                const float4* wr =
                    reinterpret_cast<const float4*>(&wl[(ci * 9 + ky * 3 + kx) * 28]);
                #pragma unroll
                for (int q = 0; q < 7; ++q) {
                    float4 wv = wr[q];
                    acc[4*q+0] += xv * wv.x;
                    acc[4*q+1] += xv * wv.y;
                    acc[4*q+2] += xv * wv.z;
                    acc[4*q+3] += xv * wv.w;
                }
            }
        }
    }

    float* ob = offs + (size_t)b * (18 * HW) + rem;
    #pragma unroll
    for (int co = 0; co < 18; ++co) ob[co * HW] = acc[co];
    float* mb = modv + (size_t)b * (9 * HW) + rem;
    #pragma unroll
    for (int j = 0; j < 9; ++j) mb[j * HW] = 2.0f / (1.0f + expf(-acc[18 + j]));
}

__global__ __launch_bounds__(256) void deform_kernel(
    const float* __restrict__ x,
    const float* __restrict__ offs, const float* __restrict__ modv,
    const float* __restrict__ w_reg, float* __restrict__ out)
{
    __shared__ float wl[288 * 32];
    const int tid = threadIdx.x;
    for (int i = tid; i < 288 * 32; i += 256) {
        int o  = i & 31;
        int ck = i >> 5;
        wl[i] = w_reg[o * 288 + ck];
    }
    __syncthreads();

    const int pos = blockIdx.x * 256 + tid;
    const int b   = pos / HW;
    const int rem = pos - b * HW;
    const int ho  = rem / W;
    const int wo  = rem - ho * W;

    const float* xb = x    + (size_t)b * (CIN * HW);
    const float* ob = offs + (size_t)b * (18 * HW) + rem;
    const float* mb = modv + (size_t)b * (9 * HW) + rem;

    float acc[32];
    #pragma unroll
    for (int o = 0; o < 32; ++o) acc[o] = 0.0f;

    for (int k = 0; k < 9; ++k) {
        const int ky = k / 3;
        const int kx = k - ky * 3;
        const float oy = ob[(2 * k) * HW];
        const float ox = ob[(2 * k + 1) * HW];
        const float m  = mb[k * HW];

        const float py  = oy + (float)(ho - 1 + ky);
        const float px  = ox + (float)(wo - 1 + kx);
        const float y0f = floorf(py);
        const float x0f = floorf(px);
        const float wy  = py - y0f;
        const float wx  = px - x0f;
        const int y0 = (int)y0f, x0 = (int)x0f;
        const int y1 = y0 + 1,  x1 = x0 + 1;

        const float vy0 = ((unsigned)y0 < (unsigned)H) ? 1.0f : 0.0f;
        const float vy1 = ((unsigned)y1 < (unsigned)H) ? 1.0f : 0.0f;
        const float vx0 = ((unsigned)x0 < (unsigned)W) ? 1.0f : 0.0f;
        const float vx1 = ((unsigned)x1 < (unsigned)W) ? 1.0f : 0.0f;

        const float w00 = (1.0f - wy) * (1.0f - wx) * vy0 * vx0 * m;
        const float w01 = (1.0f - wy) * wx          * vy0 * vx1 * m;
        const float w10 = wy * (1.0f - wx)          * vy1 * vx0 * m;
        const float w11 = wy * wx                   * vy1 * vx1 * m;

        const int cy0 = min(max(y0, 0), H - 1), cy1 = min(max(y1, 0), H - 1);
        const int cx0 = min(max(x0, 0), W - 1), cx1 = min(max(x1, 0), W - 1);
        const int l00 = cy0 * W + cx0, l01 = cy0 * W + cx1;
        const int l10 = cy1 * W + cx0, l11 = cy1 * W + cx1;

        for (int c = 0; c < CIN; ++c) {
            const float* xc = xb + c * HW;
            const float v = w00 * xc[l00] + w01 * xc[l01]
                          + w10 * xc[l10] + w11 * xc[l11];
            const float4* wr = reinterpret_cast<const float4*>(&wl[(c * 9 + k) * 32]);
            #pragma unroll
            for (int q = 0; q < 8; ++q) {
                float4 wv = wr[q];
                acc[4*q+0] += v * wv.x;
                acc[4*q+1] += v * wv.y;
                acc[4*q+2] += v * wv.z;
                acc[4*q+3] += v * wv.w;
            }
        }
    }

    float* yb = out + (size_t)b * (COUT * HW) + rem;
    #pragma unroll
    for (int o = 0; o < COUT; ++o) yb[o * HW] = acc[o];
}

// ---------------------------------------------------------------------------
extern "C" void kernel_launch(void* const* d_in, const int* in_sizes, int n_in,
                              void* d_out, int out_size, void* d_ws, size_t ws_size,
                              hipStream_t stream) {
    const float* x     = (const float*)d_in[0];
    const float* w_off = (const float*)d_in[1];
    const float* b_off = (const float*)d_in[2];
    const float* w_mod = (const float*)d_in[3];
    const float* b_mod = (const float*)d_in[4];
    const float* w_reg = (const float*)d_in[5];
    float* out = (float*)d_out;

    const size_t need_fast = (size_t)NPOS * 32 * sizeof(float);   // 18.9 MB NHWC copy
    if (ws_size >= need_fast) {
        float* xt = (float*)d_ws;
        transpose_kernel<<<dim3(NB * (HW / 64)), dim3(256), 0, stream>>>(x, xt);
        deform_mfma_kernel<<<dim3(NBLK_F), dim3(512), 0, stream>>>(
            xt, w_off, b_off, w_mod, b_mod, w_reg, out);
    } else {
        float* offs = (float*)d_ws;
        float* modv = offs + (size_t)NB * 18 * HW;
        dim3 grid(NBLK0), blk(256);
        conv_offmod_kernel<<<grid, blk, 0, stream>>>(x, w_off, b_off, w_mod, b_mod, offs, modv);
        deform_kernel<<<grid, blk, 0, stream>>>(x, offs, modv, w_reg, out);
    }
}

// Round 4
// 70.516 us; speedup vs baseline: 5.1385x; 1.8218x over previous
//
#include <hip/hip_runtime.h>
#include <hip/hip_bf16.h>
#include <math.h>

#define H 192
#define W 192
#define HW (H*W)          // 36864
#define CIN 32
#define COUT 32
#define NB 4
#define NPOS (NB*HW)      // 147456
#define NBLK_F (NPOS/128) // 1152 blocks of 512 threads (8 waves x 16 pos)
#define NBLK0 (NPOS/256)  // 576 fallback blocks

typedef __attribute__((ext_vector_type(8))) short bf16x8;
typedef __attribute__((ext_vector_type(4))) float f32x4;

__device__ __forceinline__ short f2bf(float f) {
    __hip_bfloat16 h = __float2bfloat16(f);
    short s; __builtin_memcpy(&s, &h, sizeof(s));
    return s;
}
__device__ __forceinline__ float bflo(unsigned u) {          // bf16 in low half -> f32
    return __uint_as_float(u << 16);
}
__device__ __forceinline__ float bfhi(unsigned u) {          // bf16 in high half -> f32
    return __uint_as_float(u & 0xffff0000u);
}
__device__ __forceinline__ unsigned getd(const uint4& v, int d) {  // d compile-time
    return d == 0 ? v.x : d == 1 ? v.y : d == 2 ? v.z : v.w;
}

// bijective XCD-chunked swizzle (nblk % 8 == 0)
__device__ __forceinline__ int swz8(int bid, int nblk) {
    return (bid & 7) * (nblk >> 3) + (bid >> 3);
}

// ---------------------------------------------------------------------------
// Kernel A: NCHW fp32 -> NHWC bf16 transpose of x.
// ---------------------------------------------------------------------------
__global__ __launch_bounds__(256) void transpose_bf16_kernel(
    const float* __restrict__ x, unsigned short* __restrict__ xt)
{
    __shared__ float lds[32][65];
    const int tid = threadIdx.x;
    const int b   = blockIdx.x / (HW / 64);
    const int hw0 = (blockIdx.x % (HW / 64)) * 64;
    const float* xb = x + (size_t)b * CIN * HW;

    #pragma unroll
    for (int r = 0; r < 8; ++r) {
        const int c  = (tid >> 6) + 4 * r;
        const int hw = tid & 63;
        lds[c][hw] = xb[(size_t)c * HW + hw0 + hw];
    }
    __syncthreads();

    const int hw = tid >> 2;
    const int cg = tid & 3;
    uint4 o;
    #pragma unroll
    for (int d = 0; d < 4; ++d) {
        const unsigned lo = (unsigned short)f2bf(lds[cg * 8 + 2 * d][hw]);
        const unsigned hi = (unsigned short)f2bf(lds[cg * 8 + 2 * d + 1][hw]);
        const unsigned pk = lo | (hi << 16);
        if (d == 0) o.x = pk; else if (d == 1) o.y = pk; else if (d == 2) o.z = pk; else o.w = pk;
    }
    *reinterpret_cast<uint4*>(xt + ((size_t)(b * HW + hw0 + hw)) * 32 + cg * 8) = o;
}

// ---------------------------------------------------------------------------
// Kernel B: fused MFMA deformable conv, bf16 x, 2-deep load pipeline.
// Wave = 16 positions x 4 channel-groups. om overlays b1s after phase 1.
// ---------------------------------------------------------------------------
__global__ __launch_bounds__(512, 4) void deform_mfma_kernel(
    const unsigned short* __restrict__ xt,
    const float* __restrict__ w_off, const float* __restrict__ b_off,
    const float* __restrict__ w_mod, const float* __restrict__ b_mod,
    const float* __restrict__ w_reg, float* __restrict__ out)
{
    __shared__ short b1s[9][2][64][8];   // phase1 weights; overlaid by om in phase 2
    __shared__ short b2s[9][2][64][8];   // phase2 weights
    __shared__ float bl[32];
    float* om = reinterpret_cast<float*>(&b1s[0][0][0][0]);   // 14336 B <= 18432 B

    const int tid = threadIdx.x;

    // ---- stage B-fragments: elem e of lane l = B[k = 8*(l>>4)+e][col = 16n+(l&15)]
    for (int i = tid; i < 9 * 2 * 64 * 8; i += 512) {
        const int e = i & 7, l = (i >> 3) & 63, n = (i >> 9) & 1, t = i >> 10;
        const int o = 16 * n + (l & 15);
        const int c = 8 * (l >> 4) + e;
        const int idx = c * 9 + t;
        const float v1 = (o < 18) ? w_off[o * 288 + idx]
                        : (o < 27 ? w_mod[(o - 18) * 288 + idx] : 0.0f);
        b1s[t][n][l][e] = f2bf(v1);
        b2s[t][n][l][e] = f2bf(w_reg[o * 288 + idx]);
    }
    if (tid < 32) bl[tid] = (tid < 18) ? b_off[tid] : (tid < 27 ? b_mod[tid - 18] : 0.0f);
    __syncthreads();

    const int lane = tid & 63;
    const int wv   = tid >> 6;
    const int prow = lane & 15;   // position (A row / C-D col role)
    const int kgrp = lane >> 4;   // channel group
    const int col  = prow;

    const int pos_wave = swz8(blockIdx.x, NBLK_F) * 128 + wv * 16;
    const int b    = pos_wave / HW;           // uniform per block (HW % 128 == 0)
    const int rem0 = pos_wave - b * HW;
    const int ho   = rem0 / W;
    const int wo0  = rem0 - ho * W;
    const int wo   = wo0 + prow;

    const char* xbc  = (const char*)(xt + (size_t)b * HW * 32);
    const int   kgoff = kgrp * 16;            // byte offset of this lane's 8 channels

    // ================= phase 1: offset/modulator conv (2-deep pipeline) ======
    f32x4 c10 = {0.f, 0.f, 0.f, 0.f}, c11 = {0.f, 0.f, 0.f, 0.f};
    uint4 xbuf[2]; unsigned okm[2];

    auto p1addr = [&](int t, int s) {
        const int ty = t / 3, tx = t - (t / 3) * 3;
        const int iy = ho + ty - 1, ix = wo + tx - 1;
        const bool ok = ((unsigned)iy < (unsigned)H) && ((unsigned)ix < (unsigned)W);
        const int cy = min(max(iy, 0), H - 1), cx = min(max(ix, 0), W - 1);
        okm[s]  = ok ? 0xffffffffu : 0u;
        xbuf[s] = *reinterpret_cast<const uint4*>(xbc + ((cy * W + cx) * 64 + kgoff));
    };

    p1addr(0, 0);
    #pragma unroll
    for (int t = 0; t < 9; ++t) {
        if (t < 8) p1addr(t + 1, (t + 1) & 1);
        const int s = t & 1;
        uint4 av;
        av.x = xbuf[s].x & okm[s]; av.y = xbuf[s].y & okm[s];
        av.z = xbuf[s].z & okm[s]; av.w = xbuf[s].w & okm[s];
        bf16x8 a; __builtin_memcpy(&a, &av, sizeof(a));
        const bf16x8 wb0 = *reinterpret_cast<const bf16x8*>(&b1s[t][0][lane][0]);
        const bf16x8 wb1 = *reinterpret_cast<const bf16x8*>(&b1s[t][1][lane][0]);
        c10 = __builtin_amdgcn_mfma_f32_16x16x32_bf16(a, wb0, c10, 0, 0, 0);
        c11 = __builtin_amdgcn_mfma_f32_16x16x32_bf16(a, wb1, c11, 0, 0, 0);
    }

    // ---- all waves done reading b1s -> safe to overlay om ----
    __syncthreads();

    {
        const float bias0 = bl[col], bias1 = bl[16 + col];
        float* omw = om + (wv * 16) * 28;
        #pragma unroll
        for (int r = 0; r < 4; ++r) {
            const int prc = kgrp * 4 + r;
            omw[prc * 28 + col] = c10[r] + bias0;
            if (col < 11) {
                float v = c11[r] + bias1;
                if (col >= 2) v = 2.0f / (1.0f + __expf(-v));   // ch18..26: 2*sigmoid
                omw[prc * 28 + 16 + col] = v;
            }
        }
    }
    // same-wave LDS write->read ordering handled by compiler (lgkmcnt)
    const float* omp = om + (wv * 16 + prow) * 28;

    // ================= phase 2: deform sampling + contraction (pipelined) ====
    f32x4 c20 = {0.f, 0.f, 0.f, 0.f}, c21 = {0.f, 0.f, 0.f, 0.f};
    uint4 cb[2][4]; f32x4 wtb[2];

    auto p2tap = [&](int k, int s) {
        const int ky = k / 3, kx = k - (k / 3) * 3;
        const float oy = omp[2 * k];
        const float ox = omp[2 * k + 1];
        const float m  = omp[18 + k];

        const float py  = oy + (float)(ho - 1 + ky);
        const float px  = ox + (float)(wo - 1 + kx);
        const float y0f = floorf(py);
        const float x0f = floorf(px);
        const float wy  = py - y0f;
        const float wx  = px - x0f;
        const int y0 = (int)y0f, x0 = (int)x0f;
        const int y1 = y0 + 1,  x1 = x0 + 1;

        const float vy0 = ((unsigned)y0 < (unsigned)H) ? 1.0f : 0.0f;
        const float vy1 = ((unsigned)y1 < (unsigned)H) ? 1.0f : 0.0f;
        const float vx0 = ((unsigned)x0 < (unsigned)W) ? 1.0f : 0.0f;
        const float vx1 = ((unsigned)x1 < (unsigned)W) ? 1.0f : 0.0f;

        f32x4 wt;
        wt[0] = (1.0f - wy) * (1.0f - wx) * vy0 * vx0 * m;
        wt[1] = (1.0f - wy) * wx          * vy0 * vx1 * m;
        wt[2] = wy * (1.0f - wx)          * vy1 * vx0 * m;
        wt[3] = wy * wx                   * vy1 * vx1 * m;
        wtb[s] = wt;

        const int cy0 = min(max(y0, 0), H - 1), cy1 = min(max(y1, 0), H - 1);
        const int cx0 = min(max(x0, 0), W - 1), cx1 = min(max(x1, 0), W - 1);
        const int r0 = cy0 * (W * 64), r1 = cy1 * (W * 64);
        const int c0 = cx0 * 64 + kgoff, c1 = cx1 * 64 + kgoff;
        cb[s][0] = *reinterpret_cast<const uint4*>(xbc + (r0 + c0));
        cb[s][1] = *reinterpret_cast<const uint4*>(xbc + (r0 + c1));
        cb[s][2] = *reinterpret_cast<const uint4*>(xbc + (r1 + c0));
        cb[s][3] = *reinterpret_cast<const uint4*>(xbc + (r1 + c1));
    };

    p2tap(0, 0);
    #pragma unroll
    for (int k = 0; k < 9; ++k) {
        if (k < 8) p2tap(k + 1, (k + 1) & 1);
        const int s = k & 1;
        const f32x4 w = wtb[s];
        const uint4 r00 = cb[s][0], r01 = cb[s][1], r10 = cb[s][2], r11 = cb[s][3];

        short ash[8];
        #pragma unroll
        for (int d = 0; d < 4; ++d) {
            const unsigned u00 = getd(r00, d), u01 = getd(r01, d);
            const unsigned u10 = getd(r10, d), u11 = getd(r11, d);
            const float vlo = w[0] * bflo(u00) + w[1] * bflo(u01)
                            + w[2] * bflo(u10) + w[3] * bflo(u11);
            const float vhi = w[0] * bfhi(u00) + w[1] * bfhi(u01)
                            + w[2] * bfhi(u10) + w[3] * bfhi(u11);
            ash[2 * d]     = f2bf(vlo);
            ash[2 * d + 1] = f2bf(vhi);
        }
        bf16x8 a; __builtin_memcpy(&a, ash, sizeof(a));
        const bf16x8 wb0 = *reinterpret_cast<const bf16x8*>(&b2s[k][0][lane][0]);
        const bf16x8 wb1 = *reinterpret_cast<const bf16x8*>(&b2s[k][1][lane][0]);
        c20 = __builtin_amdgcn_mfma_f32_16x16x32_bf16(a, wb0, c20, 0, 0, 0);
        c21 = __builtin_amdgcn_mfma_f32_16x16x32_bf16(a, wb1, c21, 0, 0, 0);
    }

    // ---- epilogue: C/D row = kgrp*4+r (position), col / col+16 (channel) ----
    float* yb = out + (size_t)b * COUT * HW;
    const int hwb = rem0 + kgrp * 4;
    #pragma unroll
    for (int r = 0; r < 4; ++r) {
        yb[(size_t)col * HW + hwb + r]        = c20[r];
        yb[(size_t)(col + 16) * HW + hwb + r] = c21[r];
    }
}

// ---------------------------------------------------------------------------
// Fallback path (round-0 kernels, proven; used only if ws too small)
// ---------------------------------------------------------------------------
__global__ __launch_bounds__(256) void conv_offmod_kernel(
    const float* __restrict__ x,
    const float* __restrict__ w_off, const float* __restrict__ b_off,
    const float* __restrict__ w_mod, const float* __restrict__ b_mod,
    float* __restrict__ offs, float* __restrict__ modv)
{
    __shared__ float wl[288 * 28];
    __shared__ float bl[27];
    const int tid = threadIdx.x;

    for (int i = tid; i < 288 * 27; i += 256) {
        int j  = i / 27;
        int co = i - j * 27;
        wl[j * 28 + co] = (co < 18) ? w_off[co * 288 + j] : w_mod[(co - 18) * 288 + j];
    }
    for (int i = tid; i < 288; i += 256) wl[i * 28 + 27] = 0.0f;
    if (tid < 27) bl[tid] = (tid < 18) ? b_off[tid] : b_mod[tid - 18];
    __syncthreads();

    const int pos = blockIdx.x * 256 + tid;
    const int b   = pos / HW;
    const int rem = pos - b * HW;
    const int ho  = rem / W;
    const int wo  = rem - ho * W;

    float acc[28];
    #pragma unroll
    for (int q = 0; q < 27; ++q) acc[q] = bl[q];
    acc[27] = 0.0f;

    const float* xb = x + (size_t)b * (CIN * HW);
    for (int ci = 0; ci < CIN; ++ci) {
        const float* xc = xb + ci * HW;
        #pragma unroll
        for (int ky = 0; ky < 3; ++ky) {
            const int iy = ho + ky - 1;
            const bool yok = ((unsigned)iy < (unsigned)H);
            #pragma unroll
            for (int kx = 0; kx < 3; ++kx) {
                const int ix = wo + kx - 1;
                const float xv = (yok && ((unsigned)ix < (unsigned)W)) ? xc[iy * W + ix] : 0.0f;
                const float4* wr =
                    reinterpret_cast<const float4*>(&wl[(ci * 9 + ky * 3 + kx) * 28]);
                #pragma unroll
                for (int q = 0; q < 7; ++q) {
                    float4 wv = wr[q];
                    acc[4*q+0] += xv * wv.x;
                    acc[4*q+1] += xv * wv.y;
                    acc[4*q+2] += xv * wv.z;
                    acc[4*q+3] += xv * wv.w;
                }
            }
        }
    }

    float* ob = offs + (size_t)b * (18 * HW) + rem;
    #pragma unroll
    for (int co = 0; co < 18; ++co) ob[co * HW] = acc[co];
    float* mb = modv + (size_t)b * (9 * HW) + rem;
    #pragma unroll
    for (int j = 0; j < 9; ++j) mb[j * HW] = 2.0f / (1.0f + expf(-acc[18 + j]));
}

__global__ __launch_bounds__(256) void deform_kernel(
    const float* __restrict__ x,
    const float* __restrict__ offs, const float* __restrict__ modv,
    const float* __restrict__ w_reg, float* __restrict__ out)
{
    __shared__ float wl[288 * 32];
    const int tid = threadIdx.x;
    for (int i = tid; i < 288 * 32; i += 256) {
        int o  = i & 31;
        int ck = i >> 5;
        wl[i] = w_reg[o * 288 + ck];
    }
    __syncthreads();

    const int pos = blockIdx.x * 256 + tid;
    const int b   = pos / HW;
    const int rem = pos - b * HW;
    const int ho  = rem / W;
    const int wo  = rem - ho * W;

    const float* xb = x    + (size_t)b * (CIN * HW);
    const float* ob = offs + (size_t)b * (18 * HW) + rem;
    const float* mb = modv + (size_t)b * (9 * HW) + rem;

    float acc[32];
    #pragma unroll
    for (int o = 0; o < 32; ++o) acc[o] = 0.0f;

    for (int k = 0; k < 9; ++k) {
        const int ky = k / 3;
        const int kx = k - ky * 3;
        const float oy = ob[(2 * k) * HW];
        const float ox = ob[(2 * k + 1) * HW];
        const float m  = mb[k * HW];

        const float py  = oy + (float)(ho - 1 + ky);
        const float px  = ox + (float)(wo - 1 + kx);
        const float y0f = floorf(py);
        const float x0f = floorf(px);
        const float wy  = py - y0f;
        const float wx  = px - x0f;
        const int y0 = (int)y0f, x0 = (int)x0f;
        const int y1 = y0 + 1,  x1 = x0 + 1;

        const float vy0 = ((unsigned)y0 < (unsigned)H) ? 1.0f : 0.0f;
        const float vy1 = ((unsigned)y1 < (unsigned)H) ? 1.0f : 0.0f;
        const float vx0 = ((unsigned)x0 < (unsigned)W) ? 1.0f : 0.0f;
        const float vx1 = ((unsigned)x1 < (unsigned)W) ? 1.0f : 0.0f;

        const float w00 = (1.0f - wy) * (1.0f - wx) * vy0 * vx0 * m;
        const float w01 = (1.0f - wy) * wx          * vy0 * vx1 * m;
        const float w10 = wy * (1.0f - wx)          * vy1 * vx0 * m;
        const float w11 = wy * wx                   * vy1 * vx1 * m;

        const int cy0 = min(max(y0, 0), H - 1), cy1 = min(max(y1, 0), H - 1);
        const int cx0 = min(max(x0, 0), W - 1), cx1 = min(max(x1, 0), W - 1);
        const int l00 = cy0 * W + cx0, l01 = cy0 * W + cx1;
        const int l10 = cy1 * W + cx0, l11 = cy1 * W + cx1;

        for (int c = 0; c < CIN; ++c) {
            const float* xc = xb + c * HW;
            const float v = w00 * xc[l00] + w01 * xc[l01]
                          + w10 * xc[l10] + w11 * xc[l11];
            const float4* wr = reinterpret_cast<const float4*>(&wl[(c * 9 + k) * 32]);
            #pragma unroll
            for (int q = 0; q < 8; ++q) {
                float4 wv = wr[q];
                acc[4*q+0] += v * wv.x;
                acc[4*q+1] += v * wv.y;
                acc[4*q+2] += v * wv.z;
                acc[4*q+3] += v * wv.w;
            }
        }
    }

    float* yb = out + (size_t)b * (COUT * HW) + rem;
    #pragma unroll
    for (int o = 0; o < COUT; ++o) yb[o * HW] = acc[o];
}

// ---------------------------------------------------------------------------
extern "C" void kernel_launch(void* const* d_in, const int* in_sizes, int n_in,
                              void* d_out, int out_size, void* d_ws, size_t ws_size,
                              hipStream_t stream) {
    const float* x     = (const float*)d_in[0];
    const float* w_off = (const float*)d_in[1];
    const float* b_off = (const float*)d_in[2];
    const float* w_mod = (const float*)d_in[3];
    const float* b_mod = (const float*)d_in[4];
    const float* w_reg = (const float*)d_in[5];
    float* out = (float*)d_out;

    const size_t need_fast = (size_t)NPOS * 32 * sizeof(unsigned short);  // 9.4 MB bf16 NHWC
    if (ws_size >= need_fast) {
        unsigned short* xt = (unsigned short*)d_ws;
        transpose_bf16_kernel<<<dim3(NB * (HW / 64)), dim3(256), 0, stream>>>(x, xt);
        deform_mfma_kernel<<<dim3(NBLK_F), dim3(512), 0, stream>>>(
            xt, w_off, b_off, w_mod, b_mod, w_reg, out);
    } else {
        float* offs = (float*)d_ws;
        float* modv = offs + (size_t)NB * 18 * HW;
        dim3 grid(NBLK0), blk(256);
        conv_offmod_kernel<<<grid, blk, 0, stream>>>(x, w_off, b_off, w_mod, b_mod, offs, modv);
        deform_kernel<<<grid, blk, 0, stream>>>(x, offs, modv, w_reg, out);
    }
}